// Round 8
// baseline (1608.460 us; speedup 1.0000x reference)
//
#include <hip/hip_runtime.h>

typedef __attribute__((ext_vector_type(8))) short short8;
typedef __attribute__((ext_vector_type(4))) float floatx4;
typedef __attribute__((ext_vector_type(4))) float fx4;
typedef __attribute__((ext_vector_type(4))) unsigned ux4;
typedef __attribute__((ext_vector_type(2))) unsigned ux2;

#define B_DIM 64
#define L_SEQ 2048
#define D_H   64
#define BQ    16
#define CHUNK 512
#define QK_SCALE 0.1803368801111137f   // log2(e)/8 : folded into Q in prepass

#if defined(__has_builtin)
#  if __has_builtin(__builtin_amdgcn_exp2f)
#    define EXP2(x) __builtin_amdgcn_exp2f(x)
#  else
#    define EXP2(x) exp2f(x)
#  endif
#else
#  define EXP2(x) exp2f(x)
#endif

__device__ __forceinline__ short f2bf(float f) {
    unsigned u = __builtin_bit_cast(unsigned, f);
    u += 0x7FFFu + ((u >> 16) & 1u);
    return (short)(u >> 16);
}
__device__ __forceinline__ float bf2f_lo(unsigned w) {
    return __builtin_bit_cast(float, w << 16);
}
__device__ __forceinline__ float bf2f_hi(unsigned w) {
    return __builtin_bit_cast(float, w & 0xFFFF0000u);
}
__device__ __forceinline__ unsigned pk2bf(float a, float b) {
    unsigned ua = __builtin_bit_cast(unsigned, a);
    unsigned ub = __builtin_bit_cast(unsigned, b);
    ua += 0x7FFFu + ((ua >> 16) & 1u);
    ub += 0x7FFFu + ((ub >> 16) & 1u);
    return (ua >> 16) | (ub & 0xFFFF0000u);
}
// 16B-slot XOR swizzle within a [16][512] bf16 chunk (row stride 1024 B)
__device__ __forceinline__ int sidxc(int row, int colbyte) {
    return row * 1024 + (colbyte ^ ((row & 7) << 4));
}
// old full-row swizzle for the fallback kernel ([16][2048], stride 4096 B)
__device__ __forceinline__ int sidx(int row, int colbyte) {
    return row * 4096 + (colbyte ^ ((row & 7) << 4));
}

// ================= prepass 1: Q (pre-scaled) and K -> bf16 =================
__global__ __launch_bounds__(256) void prep_qk(const float* __restrict__ q,
                                               const float* __restrict__ k,
                                               unsigned short* __restrict__ qb,
                                               unsigned short* __restrict__ kb) {
    size_t i = (size_t)blockIdx.x * 256 + threadIdx.x;     // x4 elements
    fx4 q4 = __builtin_nontemporal_load((const fx4*)q + i);
    fx4 k4 = __builtin_nontemporal_load((const fx4*)k + i);
    ux2 qo, ko;
    qo[0] = pk2bf(q4[0] * QK_SCALE, q4[1] * QK_SCALE);
    qo[1] = pk2bf(q4[2] * QK_SCALE, q4[3] * QK_SCALE);
    ko[0] = pk2bf(k4[0], k4[1]);
    ko[1] = pk2bf(k4[2], k4[3]);
    *((ux2*)qb + i) = qo;
    *((ux2*)kb + i) = ko;
}

// ================= prepass 2: V -> bf16 transposed [B][D][L] =================
__global__ __launch_bounds__(256) void prep_vt(const float* __restrict__ v,
                                               unsigned short* __restrict__ vt) {
    __shared__ float tile[64][65];
    const int b  = blockIdx.x >> 5;
    const int kc = (blockIdx.x & 31) * 64;
    const int t  = threadIdx.x;
    {
        const int r = t >> 2, c4 = (t & 3) * 16;
        const float* src = v + ((size_t)b * L_SEQ + kc + r) * D_H + c4;
        #pragma unroll
        for (int j = 0; j < 4; ++j) {
            fx4 f = __builtin_nontemporal_load((const fx4*)(src + j * 4));
            tile[r][c4 + j * 4 + 0] = f[0]; tile[r][c4 + j * 4 + 1] = f[1];
            tile[r][c4 + j * 4 + 2] = f[2]; tile[r][c4 + j * 4 + 3] = f[3];
        }
    }
    __syncthreads();
    const int d = t >> 2, kq = (t & 3) * 16;
    ux4 o0, o1;
    o0[0] = pk2bf(tile[kq + 0][d], tile[kq + 1][d]);
    o0[1] = pk2bf(tile[kq + 2][d], tile[kq + 3][d]);
    o0[2] = pk2bf(tile[kq + 4][d], tile[kq + 5][d]);
    o0[3] = pk2bf(tile[kq + 6][d], tile[kq + 7][d]);
    o1[0] = pk2bf(tile[kq + 8][d], tile[kq + 9][d]);
    o1[1] = pk2bf(tile[kq +10][d], tile[kq +11][d]);
    o1[2] = pk2bf(tile[kq +12][d], tile[kq +13][d]);
    o1[3] = pk2bf(tile[kq +14][d], tile[kq +15][d]);
    unsigned short* dst = vt + ((size_t)b * D_H + d) * L_SEQ + kc + kq;
    *(ux4*)dst = o0;
    *(ux4*)(dst + 8) = o1;
}

// ================= main kernel: 1024 threads, chunked dbuf LDS =================
__global__ __launch_bounds__(1024, 8)
void sdpa_main(const void* __restrict__ mask,
               const unsigned short* __restrict__ qb,
               const unsigned short* __restrict__ kb,
               const unsigned short* __restrict__ vt,
               float* __restrict__ out, float* __restrict__ attn)
{
    __shared__ char lds[32768];                  // 2 x [16][512] bf16 chunk buffers

    const int tid  = threadIdx.x;
    const int wave = tid >> 6;                   // 0..15
    const int lane = tid & 63;
    const int l16  = lane & 15;
    const int l4   = lane >> 4;

    const int bid  = blockIdx.x;                 // 8192, %8==0 -> bijective XCD swizzle
    const int sbid = (bid & 7) * 1024 + (bid >> 3);
    const int b     = sbid >> 7;
    const int qbase = (sbid & 127) * BQ;

    // ---------- mask element-size detection (uniform) ----------
    const unsigned* mwords = (const unsigned*)mask;
    bool wordMode = true;
    #pragma unroll 8
    for (int i = 0; i < 64; ++i) {
        unsigned w = mwords[i];
        if (!(w == 0u || w == 1u || w == 0x3F800000u)) wordMode = false;
    }

    // row ownership: row = wave; each lane owns 8 cols per chunk at c*512 + lane*8
    const size_t rowbase = ((size_t)b * L_SEQ + qbase + wave) * (size_t)L_SEQ;

    // P2b role
    const int dg = wave & 3;                     // d-group (16 cols of V)
    const int ks = wave >> 2;                    // k-quarter of each chunk (128 cols)

    const unsigned short* qrow = qb + ((size_t)b * L_SEQ + qbase + l16) * D_H + l4 * 8;
    const unsigned short* kbb  = kb + (size_t)b * L_SEQ * D_H;
    const unsigned short* vtb  = vt + ((size_t)b * D_H + dg * 16 + l16) * L_SEQ + ks * 128 + l4 * 8;

    ux4 ev[4];
    float psum = 0.f;
    floatx4 oacc = {0.f, 0.f, 0.f, 0.f};

    #pragma unroll
    for (int c = 0; c < 4; ++c) {
        char* buf = lds + (c & 1) * 16384;

        // ---- mask -> 8-bit mbits for this chunk (issued early, hidden under P1) ----
        unsigned mbits;
        if (!wordMode) {
            ux2 m = __builtin_nontemporal_load(
                (const ux2*)((const unsigned char*)mask + rowbase + c * CHUNK + lane * 8));
            unsigned lo = m[0], hi = m[1];
            mbits = ((lo & 0x000000FFu) ? 1u : 0u) | ((lo & 0x0000FF00u) ? 2u : 0u) |
                    ((lo & 0x00FF0000u) ? 4u : 0u) | ((lo & 0xFF000000u) ? 8u : 0u) |
                    ((hi & 0x000000FFu) ? 16u : 0u) | ((hi & 0x0000FF00u) ? 32u : 0u) |
                    ((hi & 0x00FF0000u) ? 64u : 0u) | ((hi & 0xFF000000u) ? 128u : 0u);
        } else {
            const unsigned* mp = mwords + rowbase + c * CHUNK + lane * 8;
            ux4 ma = __builtin_nontemporal_load((const ux4*)mp);
            ux4 mb = __builtin_nontemporal_load((const ux4*)mp + 1);
            mbits = (ma[0] ? 1u : 0u) | (ma[1] ? 2u : 0u) | (ma[2] ? 4u : 0u) | (ma[3] ? 8u : 0u) |
                    (mb[0] ? 16u : 0u) | (mb[1] ? 32u : 0u) | (mb[2] ? 64u : 0u) | (mb[3] ? 128u : 0u);
        }

        // ---- P1: this wave computes 2 k-tiles (32 cols) of S for all 16 rows ----
        {
            const int kt0 = c * 32 + wave * 2;
            const unsigned short* kr0 = kbb + (size_t)(kt0 * 16 + l16) * D_H + l4 * 8;
            const unsigned short* kr1 = kr0 + 16 * D_H;
            short8 aq0 = *(const short8*)qrow;
            short8 aq1 = *(const short8*)(qrow + 32);
            short8 b00 = *(const short8*)kr0;
            short8 b01 = *(const short8*)(kr0 + 32);
            short8 b10 = *(const short8*)kr1;
            short8 b11 = *(const short8*)(kr1 + 32);
            floatx4 s0 = {0.f, 0.f, 0.f, 0.f};
            floatx4 s1 = {0.f, 0.f, 0.f, 0.f};
            s0 = __builtin_amdgcn_mfma_f32_16x16x32_bf16(aq0, b00, s0, 0, 0, 0);
            s0 = __builtin_amdgcn_mfma_f32_16x16x32_bf16(aq1, b01, s0, 0, 0, 0);
            s1 = __builtin_amdgcn_mfma_f32_16x16x32_bf16(aq0, b10, s1, 0, 0, 0);
            s1 = __builtin_amdgcn_mfma_f32_16x16x32_bf16(aq1, b11, s1, 0, 0, 0);
            const int cb0 = (wave * 2 * 16 + l16) * 2;
            const int cb1 = cb0 + 32;
            #pragma unroll
            for (int r = 0; r < 4; ++r) {
                *(short*)(buf + sidxc(l4 * 4 + r, cb0)) = f2bf(s0[r]);
                *(short*)(buf + sidxc(l4 * 4 + r, cb1)) = f2bf(s1[r]);
            }
        }
        __syncthreads();                         // scores chunk ready

        // ---- 2a: e = mask ? 0 : exp2(s); accumulate raw f32 psum; pack bf16 ----
        {
            ux4 sw = *(ux4*)(buf + sidxc(wave, lane * 16));
            float e0 = EXP2(bf2f_lo(sw[0])), e1 = EXP2(bf2f_hi(sw[0]));
            float e2 = EXP2(bf2f_lo(sw[1])), e3 = EXP2(bf2f_hi(sw[1]));
            float e4 = EXP2(bf2f_lo(sw[2])), e5 = EXP2(bf2f_hi(sw[2]));
            float e6 = EXP2(bf2f_lo(sw[3])), e7 = EXP2(bf2f_hi(sw[3]));
            e0 = (mbits & 1u)   ? 0.f : e0;
            e1 = (mbits & 2u)   ? 0.f : e1;
            e2 = (mbits & 4u)   ? 0.f : e2;
            e3 = (mbits & 8u)   ? 0.f : e3;
            e4 = (mbits & 16u)  ? 0.f : e4;
            e5 = (mbits & 32u)  ? 0.f : e5;
            e6 = (mbits & 64u)  ? 0.f : e6;
            e7 = (mbits & 128u) ? 0.f : e7;
            psum += ((e0 + e1) + (e2 + e3)) + ((e4 + e5) + (e6 + e7));
            ev[c][0] = pk2bf(e0, e1); ev[c][1] = pk2bf(e2, e3);
            ev[c][2] = pk2bf(e4, e5); ev[c][3] = pk2bf(e6, e7);
            *(ux4*)(buf + sidxc(wave, lane * 16)) = ev[c];
        }
        __syncthreads();                         // P chunk ready for PV

        // ---- 2b: oacc += P[16 x 128-quarter] x V ----
        #pragma unroll
        for (int s = 0; s < 4; ++s) {
            short8 vf = *(const short8*)(vtb + c * CHUNK + s * 32);
            short8 pf = *(short8*)(buf + sidxc(l16, ks * 256 + s * 64 + l4 * 16));
            oacc = __builtin_amdgcn_mfma_f32_16x16x32_bf16(pf, vf, oacc, 0, 0, 0);
        }
        // next iteration's P1 writes the OTHER buffer -> no barrier needed here
    }

    // ---- row sum -> ri (full-wave butterfly; every lane of the row-wave gets it) ----
    #pragma unroll
    for (int off = 1; off < 64; off <<= 1) psum += __shfl_xor(psum, off, 64);
    const float ri = 1.0f / psum;

    // ---- attn write from registers ----
    {
        float* arow = attn + rowbase;
        #pragma unroll
        for (int c = 0; c < 4; ++c) {
            fx4 o0, o1;
            o0[0] = bf2f_lo(ev[c][0]) * ri; o0[1] = bf2f_hi(ev[c][0]) * ri;
            o0[2] = bf2f_lo(ev[c][1]) * ri; o0[3] = bf2f_hi(ev[c][1]) * ri;
            o1[0] = bf2f_lo(ev[c][2]) * ri; o1[1] = bf2f_hi(ev[c][2]) * ri;
            o1[2] = bf2f_lo(ev[c][3]) * ri; o1[3] = bf2f_hi(ev[c][3]) * ri;
            *(fx4*)(arow + c * CHUNK + lane * 8)     = o0;
            *(fx4*)(arow + c * CHUNK + lane * 8 + 4) = o1;
        }
    }

    // ---- combine 4 k-quarter partials (overlay buf0: [4][16][64] f32 = 16 KB) ----
    float* s_comb = (float*)lds;
    #pragma unroll
    for (int r = 0; r < 4; ++r)
        s_comb[ks * 1024 + (l4 * 4 + r) * 64 + dg * 16 + l16] = oacc[r];
    __syncthreads();
    {
        const int idx = wave * 64 + lane;        // q = wave (same row-wave -> ri in reg)
        float o = (s_comb[idx] + s_comb[1024 + idx]) +
                  (s_comb[2048 + idx] + s_comb[3072 + idx]);
        out[((size_t)b * L_SEQ + qbase + wave) * D_H + lane] = o * ri;
    }
}

// ================= fallback (no workspace): round-7 monolithic kernel =================
#define FB_SC_BYTES  (BQ * L_SEQ * 2)
#define FB_CB_OFF    FB_SC_BYTES
#define FB_RI_OFF    (FB_CB_OFF + 8192)
#define FB_LDS_TOTAL (FB_RI_OFF + 64)

__global__ __launch_bounds__(512, 4)
void sdpa_fb(const float* __restrict__ qf, const float* __restrict__ kf,
             const float* __restrict__ vf32, const void* __restrict__ mask,
             float* __restrict__ out, float* __restrict__ attn)
{
    extern __shared__ char lds[];
    float* s_rinv = (float*)(lds + FB_RI_OFF);

    const int tid  = threadIdx.x;
    const int wave = tid >> 6;
    const int lane = tid & 63;
    const int l16  = lane & 15;
    const int l4   = lane >> 4;

    const int bid  = blockIdx.x;
    const int sbid = (bid & 7) * 1024 + (bid >> 3);
    const int b     = sbid >> 7;
    const int qbase = (sbid & 127) * BQ;

    const unsigned* mwords = (const unsigned*)mask;
    bool wordMode = true;
    #pragma unroll 8
    for (int i = 0; i < 64; ++i) {
        unsigned w = mwords[i];
        if (!(w == 0u || w == 1u || w == 0x3F800000u)) wordMode = false;
    }

    const int qa = tid >> 5;
    const int ca = tid & 31;
    const size_t rowbase = ((size_t)b * L_SEQ + qbase + qa) * (size_t)L_SEQ;

    ux2 mm[8];
    if (!wordMode) {
        #pragma unroll
        for (int j = 0; j < 8; ++j)
            mm[j] = __builtin_nontemporal_load(
                (const ux2*)((const unsigned char*)mask + rowbase + ca * 8 + j * 256));
    }

    short8 aq0, aq1;
    {
        const float* qrow = qf + ((size_t)b * L_SEQ + qbase + l16) * D_H + l4 * 8;
        #pragma unroll
        for (int h = 0; h < 2; ++h) {
            float4 f0 = *(const float4*)(qrow + h * 32);
            float4 f1 = *(const float4*)(qrow + h * 32 + 4);
            short8 a;
            a[0] = f2bf(f0.x * QK_SCALE); a[1] = f2bf(f0.y * QK_SCALE);
            a[2] = f2bf(f0.z * QK_SCALE); a[3] = f2bf(f0.w * QK_SCALE);
            a[4] = f2bf(f1.x * QK_SCALE); a[5] = f2bf(f1.y * QK_SCALE);
            a[6] = f2bf(f1.z * QK_SCALE); a[7] = f2bf(f1.w * QK_SCALE);
            if (h == 0) aq0 = a; else aq1 = a;
        }
    }
    #pragma unroll 2
    for (int t = 0; t < 16; ++t) {
        const int kt = wave * 16 + t;
        const float* krow = kf + ((size_t)b * L_SEQ + kt * 16 + l16) * D_H + l4 * 8;
        floatx4 c = {0.f, 0.f, 0.f, 0.f};
        #pragma unroll
        for (int h = 0; h < 2; ++h) {
            float4 f0 = *(const float4*)(krow + h * 32);
            float4 f1 = *(const float4*)(krow + h * 32 + 4);
            short8 bk;
            bk[0] = f2bf(f0.x); bk[1] = f2bf(f0.y); bk[2] = f2bf(f0.z); bk[3] = f2bf(f0.w);
            bk[4] = f2bf(f1.x); bk[5] = f2bf(f1.y); bk[6] = f2bf(f1.z); bk[7] = f2bf(f1.w);
            c = __builtin_amdgcn_mfma_f32_16x16x32_bf16(h ? aq1 : aq0, bk, c, 0, 0, 0);
        }
        #pragma unroll
        for (int r = 0; r < 4; ++r)
            *(short*)(lds + sidx(l4 * 4 + r, (kt * 16 + l16) * 2)) = f2bf(c[r]);
    }
    __syncthreads();

    ux4 ev[8];
    float psum = 0.f;
    #pragma unroll 2
    for (int j = 0; j < 8; ++j) {
        const int col = ca * 8 + j * 256;
        ux4 sw = *(ux4*)(lds + sidx(qa, col * 2));
        unsigned mbits;
        if (!wordMode) {
            unsigned lo = mm[j][0], hi = mm[j][1];
            mbits = ((lo & 0x000000FFu) ? 1u : 0u) | ((lo & 0x0000FF00u) ? 2u : 0u) |
                    ((lo & 0x00FF0000u) ? 4u : 0u) | ((lo & 0xFF000000u) ? 8u : 0u) |
                    ((hi & 0x000000FFu) ? 16u : 0u) | ((hi & 0x0000FF00u) ? 32u : 0u) |
                    ((hi & 0x00FF0000u) ? 64u : 0u) | ((hi & 0xFF000000u) ? 128u : 0u);
        } else {
            const unsigned* mp = mwords + rowbase + col;
            ux4 ma = __builtin_nontemporal_load((const ux4*)mp);
            ux4 mb = __builtin_nontemporal_load((const ux4*)mp + 1);
            mbits = (ma[0] ? 1u : 0u) | (ma[1] ? 2u : 0u) | (ma[2] ? 4u : 0u) | (ma[3] ? 8u : 0u) |
                    (mb[0] ? 16u : 0u) | (mb[1] ? 32u : 0u) | (mb[2] ? 64u : 0u) | (mb[3] ? 128u : 0u);
        }
        float e0 = EXP2(bf2f_lo(sw[0])), e1 = EXP2(bf2f_hi(sw[0]));
        float e2 = EXP2(bf2f_lo(sw[1])), e3 = EXP2(bf2f_hi(sw[1]));
        float e4 = EXP2(bf2f_lo(sw[2])), e5 = EXP2(bf2f_hi(sw[2]));
        float e6 = EXP2(bf2f_lo(sw[3])), e7 = EXP2(bf2f_hi(sw[3]));
        e0 = (mbits & 1u)   ? 0.f : e0;  e1 = (mbits & 2u)   ? 0.f : e1;
        e2 = (mbits & 4u)   ? 0.f : e2;  e3 = (mbits & 8u)   ? 0.f : e3;
        e4 = (mbits & 16u)  ? 0.f : e4;  e5 = (mbits & 32u)  ? 0.f : e5;
        e6 = (mbits & 64u)  ? 0.f : e6;  e7 = (mbits & 128u) ? 0.f : e7;
        psum += ((e0 + e1) + (e2 + e3)) + ((e4 + e5) + (e6 + e7));
        ev[j][0] = pk2bf(e0, e1); ev[j][1] = pk2bf(e2, e3);
        ev[j][2] = pk2bf(e4, e5); ev[j][3] = pk2bf(e6, e7);
        *(ux4*)(lds + sidx(qa, col * 2)) = ev[j];
    }
    #pragma unroll
    for (int off = 1; off < 32; off <<= 1) psum += __shfl_xor(psum, off, 64);
    const float ri = 1.0f / psum;
    if (ca == 0) s_rinv[qa] = ri;

    {
        float* arow = attn + rowbase;
        #pragma unroll 2
        for (int j = 0; j < 8; ++j) {
            const int col = ca * 8 + j * 256;
            fx4 o0, o1;
            o0[0] = bf2f_lo(ev[j][0]) * ri; o0[1] = bf2f_hi(ev[j][0]) * ri;
            o0[2] = bf2f_lo(ev[j][1]) * ri; o0[3] = bf2f_hi(ev[j][1]) * ri;
            o1[0] = bf2f_lo(ev[j][2]) * ri; o1[1] = bf2f_hi(ev[j][2]) * ri;
            o1[2] = bf2f_lo(ev[j][3]) * ri; o1[3] = bf2f_hi(ev[j][3]) * ri;
            *(fx4*)(arow + col)     = o0;
            *(fx4*)(arow + col + 4) = o1;
        }
    }
    __syncthreads();

    const int dg = wave & 3;
    const int kh = wave >> 2;
    floatx4 oacc = {0.f, 0.f, 0.f, 0.f};
    const float* vp0 = vf32 + ((size_t)b * L_SEQ + kh * 32 + l4 * 8) * D_H + dg * 16 + l16;
    for (int ch = 0; ch < 32; ++ch) {
        const float* vp = vp0 + (size_t)ch * 64 * D_H;
        short8 vfr;
        #pragma unroll
        for (int i = 0; i < 8; ++i) vfr[i] = f2bf(vp[i * D_H]);
        short8 pf = *(short8*)(lds + sidx(l16, ch * 128 + kh * 64 + l4 * 16));
        oacc = __builtin_amdgcn_mfma_f32_16x16x32_bf16(pf, vfr, oacc, 0, 0, 0);
    }

    float* s_comb = (float*)(lds + FB_CB_OFF);
    #pragma unroll
    for (int r = 0; r < 4; ++r)
        s_comb[kh * 1024 + (l4 * 4 + r) * 64 + dg * 16 + l16] = oacc[r];
    __syncthreads();
    if (tid < 256) {
        const int qo = tid >> 4, dc = tid & 15;
        float4 a = *(float4*)(s_comb + qo * 64 + dc * 4);
        float4 c = *(float4*)(s_comb + 1024 + qo * 64 + dc * 4);
        const float rio = s_rinv[qo];
        fx4 o;
        o[0] = (a.x + c.x) * rio; o[1] = (a.y + c.y) * rio;
        o[2] = (a.z + c.z) * rio; o[3] = (a.w + c.w) * rio;
        *(fx4*)(out + ((size_t)b * L_SEQ + qbase + qo) * D_H + dc * 4) = o;
    }
}

extern "C" void kernel_launch(void* const* d_in, const int* in_sizes, int n_in,
                              void* d_out, int out_size, void* d_ws, size_t ws_size,
                              hipStream_t stream) {
    const float* q = (const float*)d_in[0];
    const float* k = (const float*)d_in[1];
    const float* v = (const float*)d_in[2];
    const void* mask = d_in[3];
    float* out  = (float*)d_out;
    float* attn = out + (size_t)B_DIM * L_SEQ * D_H;

    const size_t NE = (size_t)B_DIM * L_SEQ * D_H;          // 8,388,608
    dim3 grid(B_DIM * (L_SEQ / BQ), 1, 1);                  // 8192

    if (ws_size >= NE * 2 * 3) {
        unsigned short* qb = (unsigned short*)d_ws;
        unsigned short* kb = qb + NE;
        unsigned short* vt = kb + NE;
        hipLaunchKernelGGL(prep_qk, dim3(8192), dim3(256), 0, stream, q, k, qb, kb);
        hipLaunchKernelGGL(prep_vt, dim3(2048), dim3(256), 0, stream, v, vt);
        hipLaunchKernelGGL(sdpa_main, grid, dim3(1024, 1, 1), 0, stream,
                           mask, qb, kb, vt, out, attn);
    } else {
        hipLaunchKernelGGL(sdpa_fb, grid, dim3(512, 1, 1), FB_LDS_TOTAL, stream,
                           q, k, v, mask, out, attn);
    }
}

// Round 9
// 1050.038 us; speedup vs baseline: 1.5318x; 1.5318x over previous
//
#include <hip/hip_runtime.h>

typedef __attribute__((ext_vector_type(8))) short short8;
typedef __attribute__((ext_vector_type(4))) float floatx4;
typedef __attribute__((ext_vector_type(4))) float fx4;
typedef __attribute__((ext_vector_type(2))) float fx2;
typedef __attribute__((ext_vector_type(4))) unsigned ux4;
typedef __attribute__((ext_vector_type(2))) unsigned ux2;

#define B_DIM 64
#define L_SEQ 2048
#define D_H   64
#define BQ    16
#define QK_SCALE 0.1803368801111137f   // log2(e)/8 : folded into Q in prepass

#if defined(__has_builtin)
#  if __has_builtin(__builtin_amdgcn_exp2f)
#    define EXP2(x) __builtin_amdgcn_exp2f(x)
#  else
#    define EXP2(x) exp2f(x)
#  endif
#else
#  define EXP2(x) exp2f(x)
#endif

__device__ __forceinline__ short f2bf(float f) {
    unsigned u = __builtin_bit_cast(unsigned, f);
    u += 0x7FFFu + ((u >> 16) & 1u);
    return (short)(u >> 16);
}
__device__ __forceinline__ float bf2f_lo(unsigned w) {
    return __builtin_bit_cast(float, w << 16);
}
__device__ __forceinline__ float bf2f_hi(unsigned w) {
    return __builtin_bit_cast(float, w & 0xFFFF0000u);
}
__device__ __forceinline__ unsigned pk2bf(float a, float b) {
    unsigned ua = __builtin_bit_cast(unsigned, a);
    unsigned ub = __builtin_bit_cast(unsigned, b);
    ua += 0x7FFFu + ((ua >> 16) & 1u);
    ub += 0x7FFFu + ((ub >> 16) & 1u);
    return (ua >> 16) | (ub & 0xFFFF0000u);
}
// fallback-kernel swizzle ([16][2048] bf16, stride 4096 B)
__device__ __forceinline__ int sidx(int row, int colbyte) {
    return row * 4096 + (colbyte ^ ((row & 7) << 4));
}

// ================= prepass 1: Q (pre-scaled) and K -> bf16 =================
__global__ __launch_bounds__(256) void prep_qk(const float* __restrict__ q,
                                               const float* __restrict__ k,
                                               unsigned short* __restrict__ qb,
                                               unsigned short* __restrict__ kb) {
    size_t i = (size_t)blockIdx.x * 256 + threadIdx.x;     // x4 elements
    fx4 q4 = __builtin_nontemporal_load((const fx4*)q + i);
    fx4 k4 = __builtin_nontemporal_load((const fx4*)k + i);
    ux2 qo, ko;
    qo[0] = pk2bf(q4[0] * QK_SCALE, q4[1] * QK_SCALE);
    qo[1] = pk2bf(q4[2] * QK_SCALE, q4[3] * QK_SCALE);
    ko[0] = pk2bf(k4[0], k4[1]);
    ko[1] = pk2bf(k4[2], k4[3]);
    *((ux2*)qb + i) = qo;
    *((ux2*)kb + i) = ko;
}

// ================= prepass 2: V -> bf16 transposed [B][D][L] =================
__global__ __launch_bounds__(256) void prep_vt(const float* __restrict__ v,
                                               unsigned short* __restrict__ vt) {
    __shared__ float tile[64][65];
    const int b  = blockIdx.x >> 5;
    const int kc = (blockIdx.x & 31) * 64;
    const int t  = threadIdx.x;
    {
        const int r = t >> 2, c4 = (t & 3) * 16;
        const float* src = v + ((size_t)b * L_SEQ + kc + r) * D_H + c4;
        #pragma unroll
        for (int j = 0; j < 4; ++j) {
            fx4 f = __builtin_nontemporal_load((const fx4*)(src + j * 4));
            tile[r][c4 + j * 4 + 0] = f[0]; tile[r][c4 + j * 4 + 1] = f[1];
            tile[r][c4 + j * 4 + 2] = f[2]; tile[r][c4 + j * 4 + 3] = f[3];
        }
    }
    __syncthreads();
    const int d = t >> 2, kq = (t & 3) * 16;
    ux4 o0, o1;
    o0[0] = pk2bf(tile[kq + 0][d], tile[kq + 1][d]);
    o0[1] = pk2bf(tile[kq + 2][d], tile[kq + 3][d]);
    o0[2] = pk2bf(tile[kq + 4][d], tile[kq + 5][d]);
    o0[3] = pk2bf(tile[kq + 6][d], tile[kq + 7][d]);
    o1[0] = pk2bf(tile[kq + 8][d], tile[kq + 9][d]);
    o1[1] = pk2bf(tile[kq +10][d], tile[kq +11][d]);
    o1[2] = pk2bf(tile[kq +12][d], tile[kq +13][d]);
    o1[3] = pk2bf(tile[kq +14][d], tile[kq +15][d]);
    unsigned short* dst = vt + ((size_t)b * D_H + d) * L_SEQ + kc + kq;
    *(ux4*)dst = o0;
    *(ux4*)(dst + 8) = o1;
}

// ================= main kernel: register softmax via swapped QK^T =================
// 512 threads, 8 waves. Wave w owns k-section [w*256, w*256+256) for all 16 q-rows.
// Lane (l16,l4): q = l16. QK mfma(K,Q) -> lane holds S[q=l16][k=base+4*l4+r].
// ONE barrier total.
#define CMB_STRIDE 68                      // [8][16][68] f32 combine, padded
#define CMB_FLOATS (8 * 16 * CMB_STRIDE)   // 8704
#define RS_FLOATS  (8 * 16)

__global__ __launch_bounds__(512, 2)
void sdpa_main(const void* __restrict__ mask,
               const unsigned short* __restrict__ qb,
               const unsigned short* __restrict__ kbuf,
               const unsigned short* __restrict__ vt,
               float* __restrict__ out, float* __restrict__ attn)
{
    __shared__ float lds_f[CMB_FLOATS + RS_FLOATS];
    float* comb = lds_f;
    float* rsum = lds_f + CMB_FLOATS;

    const int tid  = threadIdx.x;
    const int wave = tid >> 6;
    const int lane = tid & 63;
    const int l16  = lane & 15;
    const int l4   = lane >> 4;

    const int bid  = blockIdx.x;               // 8192, %8==0 -> bijective XCD swizzle
    const int sbid = (bid & 7) * 1024 + (bid >> 3);
    const int b     = sbid >> 7;
    const int qbase = (sbid & 127) * BQ;

    // ---------- mask element-size detection (uniform) ----------
    const unsigned* mwords = (const unsigned*)mask;
    bool wordMode = true;
    #pragma unroll 8
    for (int i = 0; i < 64; ++i) {
        unsigned w = mwords[i];
        if (!(w == 0u || w == 1u || w == 0x3F800000u)) wordMode = false;
    }

    const int kS = wave * 256;                 // this wave's k-section
    const size_t qrow_g = (size_t)b * L_SEQ + qbase + l16;   // this lane's q row
    const size_t mrowbase = qrow_g * (size_t)L_SEQ;

    // Q fragment (B-operand): col=q=l16, k-dim=d
    const unsigned short* qrow = qb + qrow_g * D_H + l4 * 8;
    const short8 aq0 = *(const short8*)(qrow);
    const short8 aq1 = *(const short8*)(qrow + 32);

    const unsigned short* kbb = kbuf + (size_t)b * L_SEQ * D_H;
    const unsigned short* vtB = vt + ((size_t)b * D_H + l16) * L_SEQ + kS + l4 * 8;

    // shuffle sources (constant per lane)
    const int srcA = l16 + 16 * ((2 * l4) & 3);
    const int srcB = srcA + 16;
    const bool useB = (l4 >= 2);

    unsigned evA0[8], evA1[8], evB0[8], evB1[8];
    float psum = 0.f;
    floatx4 oa0 = {0.f,0.f,0.f,0.f}, oa1 = {0.f,0.f,0.f,0.f};
    floatx4 oa2 = {0.f,0.f,0.f,0.f}, oa3 = {0.f,0.f,0.f,0.f};

    #pragma unroll
    for (int c2 = 0; c2 < 8; ++c2) {
        const int kb0 = kS + c2 * 32;
        // ---- mask bits for k = kb0+4*l4+{0..3} and +16+{0..3} (byte semantics) ----
        unsigned md0, md1;
        if (!wordMode) {
            const unsigned char* mb = (const unsigned char*)mask + mrowbase + kb0 + 4 * l4;
            md0 = *(const unsigned*)(mb);
            md1 = *(const unsigned*)(mb + 16);
        } else {
            const unsigned* mw = mwords + mrowbase + kb0 + 4 * l4;
            ux4 w0 = *(const ux4*)(mw);
            ux4 w1 = *(const ux4*)(mw + 16);
            md0 = (w0[0] ? 0xFFu : 0u) | (w0[1] ? 0xFF00u : 0u) |
                  (w0[2] ? 0xFF0000u : 0u) | (w0[3] ? 0xFF000000u : 0u);
            md1 = (w1[0] ? 0xFFu : 0u) | (w1[1] ? 0xFF00u : 0u) |
                  (w1[2] ? 0xFF0000u : 0u) | (w1[3] ? 0xFF000000u : 0u);
        }

        // ---- QK^T (swapped): A = K rows, B = Q -> S[q=l16][k=kb0+4*l4+r] ----
        const unsigned short* krA = kbb + (size_t)(kb0 + l16) * D_H + l4 * 8;
        short8 kA0 = *(const short8*)(krA);
        short8 kA1 = *(const short8*)(krA + 32);
        short8 kB0 = *(const short8*)(krA + 16 * D_H);
        short8 kB1 = *(const short8*)(krA + 16 * D_H + 32);
        floatx4 sA = {0.f,0.f,0.f,0.f}, sB = {0.f,0.f,0.f,0.f};
        sA = __builtin_amdgcn_mfma_f32_16x16x32_bf16(kA0, aq0, sA, 0, 0, 0);
        sA = __builtin_amdgcn_mfma_f32_16x16x32_bf16(kA1, aq1, sA, 0, 0, 0);
        sB = __builtin_amdgcn_mfma_f32_16x16x32_bf16(kB0, aq0, sB, 0, 0, 0);
        sB = __builtin_amdgcn_mfma_f32_16x16x32_bf16(kB1, aq1, sB, 0, 0, 0);

        // ---- masked exp2 (Q pre-scaled by log2e/8) ----
        float eA0 = (md0 & 0x000000FFu) ? 0.f : EXP2(sA[0]);
        float eA1 = (md0 & 0x0000FF00u) ? 0.f : EXP2(sA[1]);
        float eA2 = (md0 & 0x00FF0000u) ? 0.f : EXP2(sA[2]);
        float eA3 = (md0 & 0xFF000000u) ? 0.f : EXP2(sA[3]);
        float eB0 = (md1 & 0x000000FFu) ? 0.f : EXP2(sB[0]);
        float eB1 = (md1 & 0x0000FF00u) ? 0.f : EXP2(sB[1]);
        float eB2 = (md1 & 0x00FF0000u) ? 0.f : EXP2(sB[2]);
        float eB3 = (md1 & 0xFF000000u) ? 0.f : EXP2(sB[3]);
        psum += ((eA0 + eA1) + (eA2 + eA3)) + ((eB0 + eB1) + (eB2 + eB3));

        unsigned EA0 = pk2bf(eA0, eA1), EA1 = pk2bf(eA2, eA3);
        unsigned EB0 = pk2bf(eB0, eB1), EB1 = pk2bf(eB2, eB3);
        evA0[c2] = EA0; evA1[c2] = EA1; evB0[c2] = EB0; evB1[c2] = EB1;

        // ---- regroup P into PV A-fragment: lane needs k-pairs (8*l4 .. 8*l4+7) ----
        unsigned xa0 = (unsigned)__shfl((int)EA0, srcA, 64);
        unsigned yb0 = (unsigned)__shfl((int)EB0, srcA, 64);
        unsigned xa1 = (unsigned)__shfl((int)EA1, srcA, 64);
        unsigned yb1 = (unsigned)__shfl((int)EB1, srcA, 64);
        unsigned xa2 = (unsigned)__shfl((int)EA0, srcB, 64);
        unsigned yb2 = (unsigned)__shfl((int)EB0, srcB, 64);
        unsigned xa3 = (unsigned)__shfl((int)EA1, srcB, 64);
        unsigned yb3 = (unsigned)__shfl((int)EB1, srcB, 64);
        ux4 pw;
        pw[0] = useB ? yb0 : xa0;
        pw[1] = useB ? yb1 : xa1;
        pw[2] = useB ? yb2 : xa2;
        pw[3] = useB ? yb3 : xa3;
        short8 pA = __builtin_bit_cast(short8, pw);

        // ---- PV: oacc[dg] += P x V^T (B-frag: V^T[d=dg*16+l16][k=kb0+l4*8..]) ----
        {
            short8 vf0 = *(const short8*)(vtB + 0 * 16 * L_SEQ + c2 * 32);
            oa0 = __builtin_amdgcn_mfma_f32_16x16x32_bf16(pA, vf0, oa0, 0, 0, 0);
            short8 vf1 = *(const short8*)(vtB + 1 * 16 * L_SEQ + c2 * 32);
            oa1 = __builtin_amdgcn_mfma_f32_16x16x32_bf16(pA, vf1, oa1, 0, 0, 0);
            short8 vf2 = *(const short8*)(vtB + 2 * 16 * L_SEQ + c2 * 32);
            oa2 = __builtin_amdgcn_mfma_f32_16x16x32_bf16(pA, vf2, oa2, 0, 0, 0);
            short8 vf3 = *(const short8*)(vtB + 3 * 16 * L_SEQ + c2 * 32);
            oa3 = __builtin_amdgcn_mfma_f32_16x16x32_bf16(pA, vf3, oa3, 0, 0, 0);
        }
    }

    // ---- O partials -> combine LDS (pre-barrier) ----
    #pragma unroll
    for (int r = 0; r < 4; ++r) {
        const int qo = 4 * l4 + r;
        comb[wave * (16 * CMB_STRIDE) + qo * CMB_STRIDE +  0 + l16] = oa0[r];
        comb[wave * (16 * CMB_STRIDE) + qo * CMB_STRIDE + 16 + l16] = oa1[r];
        comb[wave * (16 * CMB_STRIDE) + qo * CMB_STRIDE + 32 + l16] = oa2[r];
        comb[wave * (16 * CMB_STRIDE) + qo * CMB_STRIDE + 48 + l16] = oa3[r];
    }

    // ---- section row-sum: reduce over the 4-lane l4-group (same q=l16) ----
    psum += __shfl_xor(psum, 16, 64);
    psum += __shfl_xor(psum, 32, 64);
    if (lane < 16) rsum[wave * 16 + lane] = psum;

    __syncthreads();                           // THE barrier

    // ---- ri for this lane's q row ----
    float rs = 0.f;
    #pragma unroll
    for (int w = 0; w < 8; ++w) rs += rsum[w * 16 + l16];
    const float ri = 1.0f / rs;

    // ---- attn write from registers (k = kS + c2*32 + 4*l4 [+16]) ----
    {
        float* arow = attn + mrowbase;
        #pragma unroll
        for (int c2 = 0; c2 < 8; ++c2) {
            const int col = kS + c2 * 32 + 4 * l4;
            fx4 wa, wb;
            wa[0] = bf2f_lo(evA0[c2]) * ri; wa[1] = bf2f_hi(evA0[c2]) * ri;
            wa[2] = bf2f_lo(evA1[c2]) * ri; wa[3] = bf2f_hi(evA1[c2]) * ri;
            wb[0] = bf2f_lo(evB0[c2]) * ri; wb[1] = bf2f_hi(evB0[c2]) * ri;
            wb[2] = bf2f_lo(evB1[c2]) * ri; wb[3] = bf2f_hi(evB1[c2]) * ri;
            *(fx4*)(arow + col)      = wa;
            *(fx4*)(arow + col + 16) = wb;
        }
    }

    // ---- out epilogue: each thread produces 2 elements ----
    {
        const int e0 = tid * 2;
        const int qo = e0 >> 6;
        const int d0 = e0 & 63;
        float s = 0.f;
        #pragma unroll
        for (int w = 0; w < 8; ++w) s += rsum[w * 16 + qo];
        const float rio = 1.0f / s;
        float a0 = 0.f, a1 = 0.f;
        #pragma unroll
        for (int w = 0; w < 8; ++w) {
            const float* cp = comb + w * (16 * CMB_STRIDE) + qo * CMB_STRIDE + d0;
            a0 += cp[0];
            a1 += cp[1];
        }
        fx2 o; o[0] = a0 * rio; o[1] = a1 * rio;
        *(fx2*)(out + ((size_t)b * L_SEQ + qbase + qo) * D_H + d0) = o;
    }
}

// ================= fallback (no workspace): round-7 monolithic kernel =================
#define FB_SC_BYTES  (BQ * L_SEQ * 2)
#define FB_CB_OFF    FB_SC_BYTES
#define FB_RI_OFF    (FB_CB_OFF + 8192)
#define FB_LDS_TOTAL (FB_RI_OFF + 64)

__global__ __launch_bounds__(512, 4)
void sdpa_fb(const float* __restrict__ qf, const float* __restrict__ kf,
             const float* __restrict__ vf32, const void* __restrict__ mask,
             float* __restrict__ out, float* __restrict__ attn)
{
    extern __shared__ char lds[];
    float* s_rinv = (float*)(lds + FB_RI_OFF);

    const int tid  = threadIdx.x;
    const int wave = tid >> 6;
    const int lane = tid & 63;
    const int l16  = lane & 15;
    const int l4   = lane >> 4;

    const int bid  = blockIdx.x;
    const int sbid = (bid & 7) * 1024 + (bid >> 3);
    const int b     = sbid >> 7;
    const int qbase = (sbid & 127) * BQ;

    const unsigned* mwords = (const unsigned*)mask;
    bool wordMode = true;
    #pragma unroll 8
    for (int i = 0; i < 64; ++i) {
        unsigned w = mwords[i];
        if (!(w == 0u || w == 1u || w == 0x3F800000u)) wordMode = false;
    }

    const int qa = tid >> 5;
    const int ca = tid & 31;
    const size_t rowbase = ((size_t)b * L_SEQ + qbase + qa) * (size_t)L_SEQ;

    ux2 mm[8];
    if (!wordMode) {
        #pragma unroll
        for (int j = 0; j < 8; ++j)
            mm[j] = __builtin_nontemporal_load(
                (const ux2*)((const unsigned char*)mask + rowbase + ca * 8 + j * 256));
    }

    short8 aq0, aq1;
    {
        const float* qrow = qf + ((size_t)b * L_SEQ + qbase + l16) * D_H + l4 * 8;
        #pragma unroll
        for (int h = 0; h < 2; ++h) {
            float4 f0 = *(const float4*)(qrow + h * 32);
            float4 f1 = *(const float4*)(qrow + h * 32 + 4);
            short8 a;
            a[0] = f2bf(f0.x * QK_SCALE); a[1] = f2bf(f0.y * QK_SCALE);
            a[2] = f2bf(f0.z * QK_SCALE); a[3] = f2bf(f0.w * QK_SCALE);
            a[4] = f2bf(f1.x * QK_SCALE); a[5] = f2bf(f1.y * QK_SCALE);
            a[6] = f2bf(f1.z * QK_SCALE); a[7] = f2bf(f1.w * QK_SCALE);
            if (h == 0) aq0 = a; else aq1 = a;
        }
    }
    #pragma unroll 2
    for (int t = 0; t < 16; ++t) {
        const int kt = wave * 16 + t;
        const float* krow = kf + ((size_t)b * L_SEQ + kt * 16 + l16) * D_H + l4 * 8;
        floatx4 c = {0.f, 0.f, 0.f, 0.f};
        #pragma unroll
        for (int h = 0; h < 2; ++h) {
            float4 f0 = *(const float4*)(krow + h * 32);
            float4 f1 = *(const float4*)(krow + h * 32 + 4);
            short8 bk;
            bk[0] = f2bf(f0.x); bk[1] = f2bf(f0.y); bk[2] = f2bf(f0.z); bk[3] = f2bf(f0.w);
            bk[4] = f2bf(f1.x); bk[5] = f2bf(f1.y); bk[6] = f2bf(f1.z); bk[7] = f2bf(f1.w);
            c = __builtin_amdgcn_mfma_f32_16x16x32_bf16(h ? aq1 : aq0, bk, c, 0, 0, 0);
        }
        #pragma unroll
        for (int r = 0; r < 4; ++r)
            *(short*)(lds + sidx(l4 * 4 + r, (kt * 16 + l16) * 2)) = f2bf(c[r]);
    }
    __syncthreads();

    ux4 ev[8];
    float psum = 0.f;
    #pragma unroll 2
    for (int j = 0; j < 8; ++j) {
        const int col = ca * 8 + j * 256;
        ux4 sw = *(ux4*)(lds + sidx(qa, col * 2));
        unsigned mbits;
        if (!wordMode) {
            unsigned lo = mm[j][0], hi = mm[j][1];
            mbits = ((lo & 0x000000FFu) ? 1u : 0u) | ((lo & 0x0000FF00u) ? 2u : 0u) |
                    ((lo & 0x00FF0000u) ? 4u : 0u) | ((lo & 0xFF000000u) ? 8u : 0u) |
                    ((hi & 0x000000FFu) ? 16u : 0u) | ((hi & 0x0000FF00u) ? 32u : 0u) |
                    ((hi & 0x00FF0000u) ? 64u : 0u) | ((hi & 0xFF000000u) ? 128u : 0u);
        } else {
            const unsigned* mp = mwords + rowbase + col;
            ux4 ma = __builtin_nontemporal_load((const ux4*)mp);
            ux4 mb = __builtin_nontemporal_load((const ux4*)mp + 1);
            mbits = (ma[0] ? 1u : 0u) | (ma[1] ? 2u : 0u) | (ma[2] ? 4u : 0u) | (ma[3] ? 8u : 0u) |
                    (mb[0] ? 16u : 0u) | (mb[1] ? 32u : 0u) | (mb[2] ? 64u : 0u) | (mb[3] ? 128u : 0u);
        }
        float e0 = EXP2(bf2f_lo(sw[0])), e1 = EXP2(bf2f_hi(sw[0]));
        float e2 = EXP2(bf2f_lo(sw[1])), e3 = EXP2(bf2f_hi(sw[1]));
        float e4 = EXP2(bf2f_lo(sw[2])), e5 = EXP2(bf2f_hi(sw[2]));
        float e6 = EXP2(bf2f_lo(sw[3])), e7 = EXP2(bf2f_hi(sw[3]));
        e0 = (mbits & 1u)   ? 0.f : e0;  e1 = (mbits & 2u)   ? 0.f : e1;
        e2 = (mbits & 4u)   ? 0.f : e2;  e3 = (mbits & 8u)   ? 0.f : e3;
        e4 = (mbits & 16u)  ? 0.f : e4;  e5 = (mbits & 32u)  ? 0.f : e5;
        e6 = (mbits & 64u)  ? 0.f : e6;  e7 = (mbits & 128u) ? 0.f : e7;
        psum += ((e0 + e1) + (e2 + e3)) + ((e4 + e5) + (e6 + e7));
        ev[j][0] = pk2bf(e0, e1); ev[j][1] = pk2bf(e2, e3);
        ev[j][2] = pk2bf(e4, e5); ev[j][3] = pk2bf(e6, e7);
        *(ux4*)(lds + sidx(qa, col * 2)) = ev[j];
    }
    #pragma unroll
    for (int off = 1; off < 32; off <<= 1) psum += __shfl_xor(psum, off, 64);
    const float ri = 1.0f / psum;
    if (ca == 0) s_rinv[qa] = ri;

    {
        float* arow = attn + rowbase;
        #pragma unroll 2
        for (int j = 0; j < 8; ++j) {
            const int col = ca * 8 + j * 256;
            fx4 o0, o1;
            o0[0] = bf2f_lo(ev[j][0]) * ri; o0[1] = bf2f_hi(ev[j][0]) * ri;
            o0[2] = bf2f_lo(ev[j][1]) * ri; o0[3] = bf2f_hi(ev[j][1]) * ri;
            o1[0] = bf2f_lo(ev[j][2]) * ri; o1[1] = bf2f_hi(ev[j][2]) * ri;
            o1[2] = bf2f_lo(ev[j][3]) * ri; o1[3] = bf2f_hi(ev[j][3]) * ri;
            *(fx4*)(arow + col)     = o0;
            *(fx4*)(arow + col + 4) = o1;
        }
    }
    __syncthreads();

    const int dg = wave & 3;
    const int kh = wave >> 2;
    floatx4 oacc = {0.f, 0.f, 0.f, 0.f};
    const float* vp0 = vf32 + ((size_t)b * L_SEQ + kh * 32 + l4 * 8) * D_H + dg * 16 + l16;
    for (int ch = 0; ch < 32; ++ch) {
        const float* vp = vp0 + (size_t)ch * 64 * D_H;
        short8 vfr;
        #pragma unroll
        for (int i = 0; i < 8; ++i) vfr[i] = f2bf(vp[i * D_H]);
        short8 pf = *(short8*)(lds + sidx(l16, ch * 128 + kh * 64 + l4 * 16));
        oacc = __builtin_amdgcn_mfma_f32_16x16x32_bf16(pf, vfr, oacc, 0, 0, 0);
    }

    float* s_comb = (float*)(lds + FB_CB_OFF);
    #pragma unroll
    for (int r = 0; r < 4; ++r)
        s_comb[kh * 1024 + (l4 * 4 + r) * 64 + dg * 16 + l16] = oacc[r];
    __syncthreads();
    if (tid < 256) {
        const int qo = tid >> 4, dc = tid & 15;
        float4 a = *(float4*)(s_comb + qo * 64 + dc * 4);
        float4 c = *(float4*)(s_comb + 1024 + qo * 64 + dc * 4);
        const float rio = s_rinv[qo];
        fx4 o;
        o[0] = (a.x + c.x) * rio; o[1] = (a.y + c.y) * rio;
        o[2] = (a.z + c.z) * rio; o[3] = (a.w + c.w) * rio;
        *(fx4*)(out + ((size_t)b * L_SEQ + qbase + qo) * D_H + dc * 4) = o;
    }
}

extern "C" void kernel_launch(void* const* d_in, const int* in_sizes, int n_in,
                              void* d_out, int out_size, void* d_ws, size_t ws_size,
                              hipStream_t stream) {
    const float* q = (const float*)d_in[0];
    const float* k = (const float*)d_in[1];
    const float* v = (const float*)d_in[2];
    const void* mask = d_in[3];
    float* out  = (float*)d_out;
    float* attn = out + (size_t)B_DIM * L_SEQ * D_H;

    const size_t NE = (size_t)B_DIM * L_SEQ * D_H;          // 8,388,608
    dim3 grid(B_DIM * (L_SEQ / BQ), 1, 1);                  // 8192

    if (ws_size >= NE * 2 * 3) {
        unsigned short* qb = (unsigned short*)d_ws;
        unsigned short* kb = qb + NE;
        unsigned short* vt = kb + NE;
        hipLaunchKernelGGL(prep_qk, dim3(8192), dim3(256), 0, stream, q, k, qb, kb);
        hipLaunchKernelGGL(prep_vt, dim3(2048), dim3(256), 0, stream, v, vt);
        hipLaunchKernelGGL(sdpa_main, grid, dim3(512, 1, 1), 0, stream,
                           mask, qb, kb, vt, out, attn);
    } else {
        hipLaunchKernelGGL(sdpa_fb, grid, dim3(512, 1, 1), FB_LDS_TOTAL, stream,
                           q, k, v, mask, out, attn);
    }
}